// Round 5
// baseline (1089.025 us; speedup 1.0000x reference)
//
#include <hip/hip_runtime.h>
#include <math.h>

typedef float v2f __attribute__((ext_vector_type(2)));

#define LN2_INV 1.4426950408889634f

__device__ __forceinline__ float fexp2(float x) {
#if __has_builtin(__builtin_amdgcn_exp2f)
    return __builtin_amdgcn_exp2f(x);
#else
    return exp2f(x);
#endif
}

__device__ __forceinline__ int rdlane_i(int v, int k) {
    return __builtin_amdgcn_readlane(v, k);
}

// v += dpp_shifted(v) within 16-lane rows; shifted-in lanes contribute 0.
#define DPP_ROW_ADD(V, CTRL) \
    V += __int_as_float(__builtin_amdgcn_update_dpp(0, __float_as_int(V), CTRL, 0xf, 0xf, true));

// ---------------------------------------------------------------------------
// k_h0: h0 = relu(x @ f_W + f_b), x [N,128], f_W [128,64]. 8 nodes/block.
// ---------------------------------------------------------------------------
__global__ __launch_bounds__(256) void k_h0(const float* __restrict__ x,
                                            const float* __restrict__ fW,
                                            const float* __restrict__ fb,
                                            float* __restrict__ h0) {
    __shared__ __align__(16) float xs[8 * 128];
    int t = threadIdx.x;
    int base = blockIdx.x * 8;
#pragma unroll
    for (int r = 0; r < 4; ++r) { int j = r * 256 + t; xs[j] = x[base * 128 + j]; }
    __syncthreads();
    int c = t & 63, half = t >> 6;
    float acc0 = fb[c], acc1 = fb[c];
    int m0 = half, m1 = half + 4;
#pragma unroll 8
    for (int k0 = 0; k0 < 128; k0 += 4) {
        float4 a = *(const float4*)&xs[m0 * 128 + k0];
        float4 b = *(const float4*)&xs[m1 * 128 + k0];
        float w0 = fW[(k0 + 0) * 64 + c], w1 = fW[(k0 + 1) * 64 + c];
        float w2 = fW[(k0 + 2) * 64 + c], w3 = fW[(k0 + 3) * 64 + c];
        acc0 = fmaf(a.x, w0, fmaf(a.y, w1, fmaf(a.z, w2, fmaf(a.w, w3, acc0))));
        acc1 = fmaf(b.x, w0, fmaf(b.y, w1, fmaf(b.z, w2, fmaf(b.w, w3, acc1))));
    }
    h0[(base + m0) * 64 + c] = fmaxf(acc0, 0.f);
    h0[(base + m1) * 64 + c] = fmaxf(acc1, 0.f);
}

// ---------------------------------------------------------------------------
// k_xlxr: xl = h@Wl + bl, xr = h@Wr + br, natural [N][256] layout (h*64+d).
// ---------------------------------------------------------------------------
__global__ __launch_bounds__(256) void k_xlxr(const float* __restrict__ h,
                                              const float* __restrict__ Wl,
                                              const float* __restrict__ Wr,
                                              const float* __restrict__ bl,
                                              const float* __restrict__ br,
                                              float* __restrict__ xl,
                                              float* __restrict__ xr) {
    __shared__ __align__(16) float hs[16 * 64];
    int t = threadIdx.x;
    int base = blockIdx.x * 16;
#pragma unroll
    for (int r = 0; r < 4; ++r) hs[r * 256 + t] = h[base * 64 + r * 256 + t];
    __syncthreads();
    float bL = bl[t], bR = br[t];
    float accl[16], accr[16];
#pragma unroll
    for (int m = 0; m < 16; ++m) { accl[m] = bL; accr[m] = bR; }
#pragma unroll 4
    for (int k0 = 0; k0 < 64; k0 += 4) {
        float wl[4], wr[4];
#pragma unroll
        for (int q = 0; q < 4; ++q) {
            wl[q] = Wl[(k0 + q) * 256 + t];
            wr[q] = Wr[(k0 + q) * 256 + t];
        }
#pragma unroll
        for (int m = 0; m < 16; ++m) {
            float4 hv = *(const float4*)&hs[m * 64 + k0];
            accl[m] = fmaf(hv.x, wl[0], fmaf(hv.y, wl[1], fmaf(hv.z, wl[2], fmaf(hv.w, wl[3], accl[m]))));
            accr[m] = fmaf(hv.x, wr[0], fmaf(hv.y, wr[1], fmaf(hv.z, wr[2], fmaf(hv.w, wr[3], accr[m]))));
        }
    }
#pragma unroll
    for (int m = 0; m < 16; ++m) {
        xl[(base + m) * 256 + t] = accl[m];
        xr[(base + m) * 256 + t] = accr[m];
    }
}

// ---------------------------------------------------------------------------
// CSR build. rec record (stride 24 ints): [0..19] = relu edge-MLP s_k,
// [20] = src node, [21..23] pad.
// ---------------------------------------------------------------------------
__global__ void k_zero(int* __restrict__ deg, int* __restrict__ counter, int Nn) {
    int i = blockIdx.x * 256 + threadIdx.x;
    if (i < Nn) deg[i] = 0;
    if (i == 0) *counter = 0;
}

__global__ void k_count(const int* __restrict__ dstArr, int* __restrict__ deg, int Ee) {
    int e = blockIdx.x * 256 + threadIdx.x;
    if (e < Ee) atomicAdd(&deg[dstArr[e]], 1);
}

__global__ void k_alloc(const int* __restrict__ deg, int* __restrict__ counter,
                        int* __restrict__ start, int* __restrict__ cursor, int Nn) {
    int n = blockIdx.x * 256 + threadIdx.x;
    if (n < Nn) {
        int d = deg[n];
        int b = atomicAdd(counter, d);
        start[n] = b;
        cursor[n] = b;
    }
}

__global__ void k_fill(const int* __restrict__ dstArr, const int* __restrict__ srcArr,
                       const float* __restrict__ eattr, const float* __restrict__ feW,
                       const float* __restrict__ feb, int* __restrict__ cursor,
                       int* __restrict__ rec, int Ee) {
    int e = blockIdx.x * 256 + threadIdx.x;
    if (e >= Ee) return;
    float a0 = eattr[2 * e], a1 = eattr[2 * e + 1];
    int p = atomicAdd(&cursor[dstArr[e]], 1);
    float* r = (float*)(rec + (size_t)p * 24);
    float s[20];
#pragma unroll
    for (int k = 0; k < 20; ++k)
        s[k] = fmaxf(fmaf(a0, feW[k], fmaf(a1, feW[20 + k], feb[k])), 0.f);
#pragma unroll
    for (int j = 0; j < 5; ++j)
        ((float4*)r)[j] = make_float4(s[4 * j], s[4 * j + 1], s[4 * j + 2], s[4 * j + 3]);
    ((int*)r)[20] = srcArr[e];
}

// ---------------------------------------------------------------------------
// k_edge: one wave per dst node, lane = h*16+g (natural h*64+d float4 order).
// We staged in LDS, shared across a 4-edge group (8 pk_fma per ds_read_b128).
// Score via lrelu(v) = 0.6v + 0.4|v| (abs is a free VALU modifier).
// Partial tail handled as a masked overlap group. Group-level prefetch.
// ---------------------------------------------------------------------------
__global__ __launch_bounds__(256, 3) void k_edge(
    const float4* __restrict__ xl4p, const float4* __restrict__ xr4p,
    const float* __restrict__ att, const float4* __restrict__ We4,
    const int* __restrict__ rec, const int* __restrict__ start,
    const int* __restrict__ deg, const float* __restrict__ bias,
    float* __restrict__ hout, int Nn) {
    __shared__ __align__(16) float4 swe[20 * 64];
    const int t = threadIdx.x;
#pragma unroll
    for (int j = 0; j < 5; ++j) swe[j * 256 + t] = We4[j * 256 + t];
    __syncthreads();

    const int lane = t & 63;
    const int n = (int)((blockIdx.x * 256u + t) >> 6);
    if (n >= Nn) return;

    const int dn = __builtin_amdgcn_readfirstlane(deg[n]);
    float4 bias4 = ((const float4*)bias)[lane & 15];
    if (dn == 0) {
        if (lane < 16) {
            float4 o = make_float4(fmaxf(bias4.x, 0.f), fmaxf(bias4.y, 0.f),
                                   fmaxf(bias4.z, 0.f), fmaxf(bias4.w, 0.f));
            ((float4*)hout)[(size_t)n * 16 + lane] = o;
        }
        return;
    }
    const int s0 = __builtin_amdgcn_readfirstlane(start[n]);
    const int* rb = rec + (size_t)s0 * 24 + (lane & 31);

    float4 attv = ((const float4*)att)[lane];
    float4 aA = make_float4(0.6f * LN2_INV * attv.x, 0.6f * LN2_INV * attv.y,
                            0.6f * LN2_INV * attv.z, 0.6f * LN2_INV * attv.w);
    float4 aB = make_float4(0.4f * LN2_INV * attv.x, 0.4f * LN2_INV * attv.y,
                            0.4f * LN2_INV * attv.z, 0.4f * LN2_INV * attv.w);
    float4 xrv = xr4p[(size_t)n * 64 + lane];
    v2f xr01 = {xrv.x, xrv.y}, xr23 = {xrv.z, xrv.w};
    const int bperm = ((lane & 48) | 15) << 2;

    v2f acc01 = {0.f, 0.f}, acc23 = {0.f, 0.f};
    float l = 0.f;

    const int nfull = dn >> 2;
    const int rem = dn & 3;
    const int ngroups = nfull + (rem ? 1 : 0);
    const int fb = dn >= 4 ? dn - 4 : 0;     // base of masked tail group

#define LOAD_GROUP(RV, B)                                                   \
    {                                                                       \
        _Pragma("unroll")                                                   \
        for (int j_ = 0; j_ < 4; ++j_) {                                    \
            int idx_ = (B) + j_;                                            \
            idx_ = idx_ < dn ? idx_ : dn - 1;                               \
            RV[j_] = rb[(size_t)idx_ * 24];                                 \
        }                                                                   \
    }
#define GATHER_GROUP(XL, RV)                                                \
    {                                                                       \
        _Pragma("unroll")                                                   \
        for (int j_ = 0; j_ < 4; ++j_) {                                    \
            int src_ = rdlane_i(RV[j_], 20);                                \
            XL[j_] = xl4p[(size_t)src_ * 64 + lane];                        \
        }                                                                   \
    }

    int rvA[4], rvB[4];
    float4 xlA[4], xlB[4];
    int b0 = (nfull > 0) ? 0 : fb;
    LOAD_GROUP(rvA, b0)
    GATHER_GROUP(xlA, rvA)

    for (int g = 0; g < ngroups; ++g) {
        int gn = g + 1;
        bool havenext = gn < ngroups;
        if (havenext) {
            int bn = (gn < nfull) ? (gn << 2) : fb;
            LOAD_GROUP(rvB, bn)
        }

        // ---- ee for the 4 current edges (We from LDS, shared) ----
        v2f ee01[4], ee23[4];
        {
            float4 w = swe[lane];
            v2f w01 = {w.x, w.y}, w23 = {w.z, w.w};
#pragma unroll
            for (int j = 0; j < 4; ++j) {
                float sk = __int_as_float(rdlane_i(rvA[j], 0));
                ee01[j] = sk * w01;
                ee23[j] = sk * w23;
            }
        }
#pragma unroll
        for (int k = 1; k < 20; ++k) {
            float4 w = swe[k * 64 + lane];
            v2f w01 = {w.x, w.y}, w23 = {w.z, w.w};
#pragma unroll
            for (int j = 0; j < 4; ++j) {
                float sk = __int_as_float(rdlane_i(rvA[j], k));
                ee01[j] += sk * w01;
                ee23[j] += sk * w23;
            }
        }

        if (havenext) GATHER_GROUP(xlB, rvB)

        // ---- scores ----
        int b = (g < nfull) ? (g << 2) : fb;
        int lo = (g < nfull) ? b : (nfull << 2);
        float ps[4];
#pragma unroll
        for (int j = 0; j < 4; ++j) {
            v2f v01 = {xlA[j].x, xlA[j].y};
            v2f v23 = {xlA[j].z, xlA[j].w};
            v01 = (v01 + xr01) + ee01[j];
            v23 = (v23 + xr23) + ee23[j];
            float tt = aB.x * __builtin_fabsf(v01.x);
            tt = fmaf(aA.x, v01.x, tt);
            tt = fmaf(aB.y, __builtin_fabsf(v01.y), tt);
            tt = fmaf(aA.y, v01.y, tt);
            tt = fmaf(aB.z, __builtin_fabsf(v23.x), tt);
            tt = fmaf(aA.z, v23.x, tt);
            tt = fmaf(aB.w, __builtin_fabsf(v23.y), tt);
            tt = fmaf(aA.w, v23.y, tt);
            ps[j] = tt;
        }
#pragma unroll
        for (int j = 0; j < 4; ++j) { DPP_ROW_ADD(ps[j], 0x111) }
#pragma unroll
        for (int j = 0; j < 4; ++j) { DPP_ROW_ADD(ps[j], 0x112) }
#pragma unroll
        for (int j = 0; j < 4; ++j) { DPP_ROW_ADD(ps[j], 0x114) }
#pragma unroll
        for (int j = 0; j < 4; ++j) { DPP_ROW_ADD(ps[j], 0x118) }
#pragma unroll
        for (int j = 0; j < 4; ++j) {
            float sc = __int_as_float(
                __builtin_amdgcn_ds_bpermute(bperm, __float_as_int(ps[j])));
            float mk = (b + j >= lo && b + j < dn) ? 1.f : 0.f;
            float w_ = fexp2(sc) * mk;
            l += w_;
            v2f xl01 = {xlA[j].x, xlA[j].y};
            v2f xl23 = {xlA[j].z, xlA[j].w};
            acc01 += w_ * xl01;
            acc23 += w_ * xl23;
        }

        if (havenext) {
#pragma unroll
            for (int j = 0; j < 4; ++j) { rvA[j] = rvB[j]; xlA[j] = xlB[j]; }
        }
    }
#undef LOAD_GROUP
#undef GATHER_GROUP

    // epilogue: res = relu(bias + 0.25 * sum_h acc_h / l_h)
    float inv = 0.25f / l;
    float4 r = make_float4(acc01.x * inv, acc01.y * inv, acc23.x * inv, acc23.y * inv);
    r.x += __shfl_xor(r.x, 16, 64); r.x += __shfl_xor(r.x, 32, 64);
    r.y += __shfl_xor(r.y, 16, 64); r.y += __shfl_xor(r.y, 32, 64);
    r.z += __shfl_xor(r.z, 16, 64); r.z += __shfl_xor(r.z, 32, 64);
    r.w += __shfl_xor(r.w, 16, 64); r.w += __shfl_xor(r.w, 32, 64);
    if (lane < 16) {
        float4 o = make_float4(fmaxf(r.x + bias4.x, 0.f), fmaxf(r.y + bias4.y, 0.f),
                               fmaxf(r.z + bias4.z, 0.f), fmaxf(r.w + bias4.w, 0.f));
        ((float4*)hout)[(size_t)n * 16 + lane] = o;
    }
}

// ---------------------------------------------------------------------------
extern "C" void kernel_launch(void* const* d_in, const int* in_sizes, int n_in,
                              void* d_out, int out_size, void* d_ws, size_t ws_size,
                              hipStream_t stream) {
    const float* x     = (const float*)d_in[0];
    const float* eattr = (const float*)d_in[1];
    const int*   eidx  = (const int*)d_in[2];
    const float* fW    = (const float*)d_in[3];
    const float* fb    = (const float*)d_in[4];
    const float* feW   = (const float*)d_in[5];
    const float* feb   = (const float*)d_in[6];
    const float* Wl    = (const float*)d_in[7];
    const float* bl    = (const float*)d_in[8];
    const float* Wr    = (const float*)d_in[9];
    const float* br    = (const float*)d_in[10];
    const float* We    = (const float*)d_in[11];
    const float* att   = (const float*)d_in[12];
    const float* bias  = (const float*)d_in[13];
    float* out = (float*)d_out;

    const int N = in_sizes[0] / 128;   // 50000
    const int E = in_sizes[1] / 2;     // 800000
    const int* srcArr = eidx;
    const int* dstArr = eidx + E;

    char* p = (char*)d_ws;
    auto alloc = [&](size_t bytes) -> char* {
        char* r = p;
        p += (bytes + 255) & ~(size_t)255;
        return r;
    };
    float* hA   = (float*)alloc((size_t)N * 64 * 4);
    float* hB   = (float*)alloc((size_t)N * 64 * 4);
    float* xl   = (float*)alloc((size_t)N * 256 * 4);
    float* xr   = (float*)alloc((size_t)N * 256 * 4);
    int* deg    = (int*)alloc((size_t)N * 4);
    int* start  = (int*)alloc((size_t)N * 4);
    int* cursor = (int*)alloc((size_t)N * 4);
    int* counter = (int*)alloc(256);
    int* rec    = (int*)alloc((size_t)E * 24 * 4 + 256);  // +slack for lane overread

    k_h0<<<N / 8, 256, 0, stream>>>(x, fW, fb, hA);
    k_zero<<<(N + 255) / 256, 256, 0, stream>>>(deg, counter, N);
    k_count<<<(E + 255) / 256, 256, 0, stream>>>(dstArr, deg, E);
    k_alloc<<<(N + 255) / 256, 256, 0, stream>>>(deg, counter, start, cursor, N);
    k_fill<<<(E + 255) / 256, 256, 0, stream>>>(dstArr, srcArr, eattr, feW, feb,
                                                cursor, rec, E);

    const float* hin = hA;
    for (int layer = 0; layer < 3; ++layer) {
        float* hout = (layer == 2) ? out : ((layer == 0) ? hB : hA);
        k_xlxr<<<N / 16, 256, 0, stream>>>(hin, Wl, Wr, bl, br, xl, xr);
        k_edge<<<(N * 64) / 256, 256, 0, stream>>>(
            (const float4*)xl, (const float4*)xr, att, (const float4*)We,
            rec, start, deg, bias, hout, N);
        hin = hout;
    }
}

// Round 6
// 985.289 us; speedup vs baseline: 1.1053x; 1.1053x over previous
//
#include <hip/hip_runtime.h>
#include <math.h>

typedef float v2f __attribute__((ext_vector_type(2)));

#define LN2_INV 1.4426950408889634f

__device__ __forceinline__ float fexp2(float x) {
#if __has_builtin(__builtin_amdgcn_exp2f)
    return __builtin_amdgcn_exp2f(x);
#else
    return exp2f(x);
#endif
}

// v += dpp_shifted(v) within 16-lane rows; shifted-in lanes contribute 0.
#define DPP_ROW_ADD(V, CTRL) \
    V += __int_as_float(__builtin_amdgcn_update_dpp(0, __float_as_int(V), CTRL, 0xf, 0xf, true));

// ---------------------------------------------------------------------------
// k_h0: h0 = relu(x @ f_W + f_b), x [N,128], f_W [128,64]. 8 nodes/block.
// ---------------------------------------------------------------------------
__global__ __launch_bounds__(256) void k_h0(const float* __restrict__ x,
                                            const float* __restrict__ fW,
                                            const float* __restrict__ fb,
                                            float* __restrict__ h0) {
    __shared__ __align__(16) float xs[8 * 128];
    int t = threadIdx.x;
    int base = blockIdx.x * 8;
#pragma unroll
    for (int r = 0; r < 4; ++r) { int j = r * 256 + t; xs[j] = x[base * 128 + j]; }
    __syncthreads();
    int c = t & 63, half = t >> 6;
    float acc0 = fb[c], acc1 = fb[c];
    int m0 = half, m1 = half + 4;
#pragma unroll 8
    for (int k0 = 0; k0 < 128; k0 += 4) {
        float4 a = *(const float4*)&xs[m0 * 128 + k0];
        float4 b = *(const float4*)&xs[m1 * 128 + k0];
        float w0 = fW[(k0 + 0) * 64 + c], w1 = fW[(k0 + 1) * 64 + c];
        float w2 = fW[(k0 + 2) * 64 + c], w3 = fW[(k0 + 3) * 64 + c];
        acc0 = fmaf(a.x, w0, fmaf(a.y, w1, fmaf(a.z, w2, fmaf(a.w, w3, acc0))));
        acc1 = fmaf(b.x, w0, fmaf(b.y, w1, fmaf(b.z, w2, fmaf(b.w, w3, acc1))));
    }
    h0[(base + m0) * 64 + c] = fmaxf(acc0, 0.f);
    h0[(base + m1) * 64 + c] = fmaxf(acc1, 0.f);
}

// ---------------------------------------------------------------------------
// k_xlxr: xl = h@Wl + bl, xr = h@Wr + br, natural [N][256] layout (h*64+d).
// ---------------------------------------------------------------------------
__global__ __launch_bounds__(256) void k_xlxr(const float* __restrict__ h,
                                              const float* __restrict__ Wl,
                                              const float* __restrict__ Wr,
                                              const float* __restrict__ bl,
                                              const float* __restrict__ br,
                                              float* __restrict__ xl,
                                              float* __restrict__ xr) {
    __shared__ __align__(16) float hs[16 * 64];
    int t = threadIdx.x;
    int base = blockIdx.x * 16;
#pragma unroll
    for (int r = 0; r < 4; ++r) hs[r * 256 + t] = h[base * 64 + r * 256 + t];
    __syncthreads();
    float bL = bl[t], bR = br[t];
    float accl[16], accr[16];
#pragma unroll
    for (int m = 0; m < 16; ++m) { accl[m] = bL; accr[m] = bR; }
#pragma unroll 4
    for (int k0 = 0; k0 < 64; k0 += 4) {
        float wl[4], wr[4];
#pragma unroll
        for (int q = 0; q < 4; ++q) {
            wl[q] = Wl[(k0 + q) * 256 + t];
            wr[q] = Wr[(k0 + q) * 256 + t];
        }
#pragma unroll
        for (int m = 0; m < 16; ++m) {
            float4 hv = *(const float4*)&hs[m * 64 + k0];
            accl[m] = fmaf(hv.x, wl[0], fmaf(hv.y, wl[1], fmaf(hv.z, wl[2], fmaf(hv.w, wl[3], accl[m]))));
            accr[m] = fmaf(hv.x, wr[0], fmaf(hv.y, wr[1], fmaf(hv.z, wr[2], fmaf(hv.w, wr[3], accr[m]))));
        }
    }
#pragma unroll
    for (int m = 0; m < 16; ++m) {
        xl[(base + m) * 256 + t] = accl[m];
        xr[(base + m) * 256 + t] = accr[m];
    }
}

// ---------------------------------------------------------------------------
// CSR build. rec record (stride 24 ints): [0..19] = relu edge-MLP s_k,
// [20] = src node, [21..23] pad.
// ---------------------------------------------------------------------------
__global__ void k_zero(int* __restrict__ deg, int* __restrict__ counter, int Nn) {
    int i = blockIdx.x * 256 + threadIdx.x;
    if (i < Nn) deg[i] = 0;
    if (i == 0) *counter = 0;
}

__global__ void k_count(const int* __restrict__ dstArr, int* __restrict__ deg, int Ee) {
    int e = blockIdx.x * 256 + threadIdx.x;
    if (e < Ee) atomicAdd(&deg[dstArr[e]], 1);
}

__global__ void k_alloc(const int* __restrict__ deg, int* __restrict__ counter,
                        int* __restrict__ start, int* __restrict__ cursor, int Nn) {
    int n = blockIdx.x * 256 + threadIdx.x;
    if (n < Nn) {
        int d = deg[n];
        int b = atomicAdd(counter, d);
        start[n] = b;
        cursor[n] = b;
    }
}

__global__ void k_fill(const int* __restrict__ dstArr, const int* __restrict__ srcArr,
                       const float* __restrict__ eattr, const float* __restrict__ feW,
                       const float* __restrict__ feb, int* __restrict__ cursor,
                       int* __restrict__ rec, int Ee) {
    int e = blockIdx.x * 256 + threadIdx.x;
    if (e >= Ee) return;
    float a0 = eattr[2 * e], a1 = eattr[2 * e + 1];
    int p = atomicAdd(&cursor[dstArr[e]], 1);
    float* r = (float*)(rec + (size_t)p * 24);
    float s[20];
#pragma unroll
    for (int k = 0; k < 20; ++k)
        s[k] = fmaxf(fmaf(a0, feW[k], fmaf(a1, feW[20 + k], feb[k])), 0.f);
#pragma unroll
    for (int j = 0; j < 5; ++j)
        ((float4*)r)[j] = make_float4(s[4 * j], s[4 * j + 1], s[4 * j + 2], s[4 * j + 3]);
    ((int*)r)[20] = srcArr[e];
}

// ---------------------------------------------------------------------------
// k_edge: one wave per dst node, lane = h*16+g (natural h*64+d float4 order).
// Edge records are read on the SCALAR pipe (wave-uniform pointer -> s_load);
// ee FMAs take SGPR*VGPR operands (no readlane). We staged in LDS, one
// ds_read_b128 shared across a 2-edge group. lrelu via 0.6v+0.4|v|.
// Tail: duplicate last edge, skipped by a wave-uniform branch.
// ---------------------------------------------------------------------------
__global__ __launch_bounds__(256, 4) void k_edge(
    const float4* __restrict__ xl4p, const float4* __restrict__ xr4p,
    const float* __restrict__ att, const float4* __restrict__ We4,
    const int* __restrict__ rec, const int* __restrict__ start,
    const int* __restrict__ deg, const float* __restrict__ bias,
    float* __restrict__ hout, int Nn) {
    __shared__ __align__(16) float4 swe[20 * 64];
    const int t = threadIdx.x;
#pragma unroll
    for (int j = 0; j < 5; ++j) swe[j * 256 + t] = We4[j * 256 + t];
    __syncthreads();

    const int lane = t & 63;
    const int n = (int)((blockIdx.x * 256u + t) >> 6);
    if (n >= Nn) return;

    const int dn = __builtin_amdgcn_readfirstlane(deg[n]);
    float4 bias4 = ((const float4*)bias)[lane & 15];
    if (dn == 0) {
        if (lane < 16) {
            float4 o = make_float4(fmaxf(bias4.x, 0.f), fmaxf(bias4.y, 0.f),
                                   fmaxf(bias4.z, 0.f), fmaxf(bias4.w, 0.f));
            ((float4*)hout)[(size_t)n * 16 + lane] = o;
        }
        return;
    }
    const int s0 = __builtin_amdgcn_readfirstlane(start[n]);
    const float* __restrict__ rbf = (const float*)rec + (size_t)s0 * 24;  // uniform

    float4 attv = ((const float4*)att)[lane];
    float4 aA = make_float4(0.6f * LN2_INV * attv.x, 0.6f * LN2_INV * attv.y,
                            0.6f * LN2_INV * attv.z, 0.6f * LN2_INV * attv.w);
    float4 aB = make_float4(0.4f * LN2_INV * attv.x, 0.4f * LN2_INV * attv.y,
                            0.4f * LN2_INV * attv.z, 0.4f * LN2_INV * attv.w);
    float4 xrv = xr4p[(size_t)n * 64 + lane];
    v2f xr01 = {xrv.x, xrv.y}, xr23 = {xrv.z, xrv.w};
    const int bperm = ((lane & 48) | 15) << 2;

    v2f acc01 = {0.f, 0.f}, acc23 = {0.f, 0.f};
    float l = 0.f;

    const int ngroups = (dn + 1) >> 1;

    // current group state (records read via uniform/scalar loads)
    const float* r0 = rbf;
    const float* r1 = rbf + (dn > 1 ? 24 : 0);
    int src0 = ((const int*)r0)[20];
    int src1 = ((const int*)r1)[20];
    float4 xl0 = xl4p[(size_t)src0 * 64 + lane];
    float4 xl1 = xl4p[(size_t)src1 * 64 + lane];

    for (int g = 0; g < ngroups; ++g) {
        const bool havenext = (g + 1) < ngroups;
        const float *nr0, *nr1;
        float4 nxl0, nxl1;
        if (havenext) {
            int e0n = (g + 1) << 1;
            int e1n = e0n + 1 < dn ? e0n + 1 : dn - 1;
            nr0 = rbf + (size_t)e0n * 24;
            nr1 = rbf + (size_t)e1n * 24;
            int ns0 = ((const int*)nr0)[20];
            int ns1 = ((const int*)nr1)[20];
            nxl0 = xl4p[(size_t)ns0 * 64 + lane];
            nxl1 = xl4p[(size_t)ns1 * 64 + lane];
        }

        // ---- ee for the 2 current edges: SGPR s_k * LDS We ----
        v2f eA01, eA23, eB01, eB23;
        {
            float4 w = swe[lane];
            v2f w01 = {w.x, w.y}, w23 = {w.z, w.w};
            float sa = r0[0], sb = r1[0];
            eA01 = sa * w01; eA23 = sa * w23;
            eB01 = sb * w01; eB23 = sb * w23;
        }
#pragma unroll
        for (int k = 1; k < 20; ++k) {
            float4 w = swe[k * 64 + lane];
            v2f w01 = {w.x, w.y}, w23 = {w.z, w.w};
            float sa = r0[k], sb = r1[k];
            eA01 += sa * w01; eA23 += sa * w23;
            eB01 += sb * w01; eB23 += sb * w23;
        }

        // ---- edge 0 score + accumulate ----
        {
            v2f v01 = ((v2f){xl0.x, xl0.y} + xr01) + eA01;
            v2f v23 = ((v2f){xl0.z, xl0.w} + xr23) + eA23;
            float tt = aB.x * __builtin_fabsf(v01.x);
            tt = fmaf(aA.x, v01.x, tt);
            tt = fmaf(aB.y, __builtin_fabsf(v01.y), tt);
            tt = fmaf(aA.y, v01.y, tt);
            tt = fmaf(aB.z, __builtin_fabsf(v23.x), tt);
            tt = fmaf(aA.z, v23.x, tt);
            tt = fmaf(aB.w, __builtin_fabsf(v23.y), tt);
            tt = fmaf(aA.w, v23.y, tt);
            DPP_ROW_ADD(tt, 0x111)
            DPP_ROW_ADD(tt, 0x112)
            DPP_ROW_ADD(tt, 0x114)
            DPP_ROW_ADD(tt, 0x118)
            float sc = __int_as_float(
                __builtin_amdgcn_ds_bpermute(bperm, __float_as_int(tt)));
            float w_ = fexp2(sc);
            l += w_;
            acc01 += w_ * (v2f){xl0.x, xl0.y};
            acc23 += w_ * (v2f){xl0.z, xl0.w};
        }
        // ---- edge 1 (skip duplicate tail; wave-uniform branch) ----
        if ((g << 1) + 1 < dn) {
            v2f v01 = ((v2f){xl1.x, xl1.y} + xr01) + eB01;
            v2f v23 = ((v2f){xl1.z, xl1.w} + xr23) + eB23;
            float tt = aB.x * __builtin_fabsf(v01.x);
            tt = fmaf(aA.x, v01.x, tt);
            tt = fmaf(aB.y, __builtin_fabsf(v01.y), tt);
            tt = fmaf(aA.y, v01.y, tt);
            tt = fmaf(aB.z, __builtin_fabsf(v23.x), tt);
            tt = fmaf(aA.z, v23.x, tt);
            tt = fmaf(aB.w, __builtin_fabsf(v23.y), tt);
            tt = fmaf(aA.w, v23.y, tt);
            DPP_ROW_ADD(tt, 0x111)
            DPP_ROW_ADD(tt, 0x112)
            DPP_ROW_ADD(tt, 0x114)
            DPP_ROW_ADD(tt, 0x118)
            float sc = __int_as_float(
                __builtin_amdgcn_ds_bpermute(bperm, __float_as_int(tt)));
            float w_ = fexp2(sc);
            l += w_;
            acc01 += w_ * (v2f){xl1.x, xl1.y};
            acc23 += w_ * (v2f){xl1.z, xl1.w};
        }

        if (havenext) {
            r0 = nr0; r1 = nr1; xl0 = nxl0; xl1 = nxl1;
        }
    }

    // epilogue: res = relu(bias + 0.25 * sum_h acc_h / l_h)
    float inv = 0.25f / l;
    float4 r = make_float4(acc01.x * inv, acc01.y * inv, acc23.x * inv, acc23.y * inv);
    r.x += __shfl_xor(r.x, 16, 64); r.x += __shfl_xor(r.x, 32, 64);
    r.y += __shfl_xor(r.y, 16, 64); r.y += __shfl_xor(r.y, 32, 64);
    r.z += __shfl_xor(r.z, 16, 64); r.z += __shfl_xor(r.z, 32, 64);
    r.w += __shfl_xor(r.w, 16, 64); r.w += __shfl_xor(r.w, 32, 64);
    if (lane < 16) {
        float4 o = make_float4(fmaxf(r.x + bias4.x, 0.f), fmaxf(r.y + bias4.y, 0.f),
                               fmaxf(r.z + bias4.z, 0.f), fmaxf(r.w + bias4.w, 0.f));
        ((float4*)hout)[(size_t)n * 16 + lane] = o;
    }
}

// ---------------------------------------------------------------------------
extern "C" void kernel_launch(void* const* d_in, const int* in_sizes, int n_in,
                              void* d_out, int out_size, void* d_ws, size_t ws_size,
                              hipStream_t stream) {
    const float* x     = (const float*)d_in[0];
    const float* eattr = (const float*)d_in[1];
    const int*   eidx  = (const int*)d_in[2];
    const float* fW    = (const float*)d_in[3];
    const float* fb    = (const float*)d_in[4];
    const float* feW   = (const float*)d_in[5];
    const float* feb   = (const float*)d_in[6];
    const float* Wl    = (const float*)d_in[7];
    const float* bl    = (const float*)d_in[8];
    const float* Wr    = (const float*)d_in[9];
    const float* br    = (const float*)d_in[10];
    const float* We    = (const float*)d_in[11];
    const float* att   = (const float*)d_in[12];
    const float* bias  = (const float*)d_in[13];
    float* out = (float*)d_out;

    const int N = in_sizes[0] / 128;   // 50000
    const int E = in_sizes[1] / 2;     // 800000
    const int* srcArr = eidx;
    const int* dstArr = eidx + E;

    char* p = (char*)d_ws;
    auto alloc = [&](size_t bytes) -> char* {
        char* r = p;
        p += (bytes + 255) & ~(size_t)255;
        return r;
    };
    float* hA   = (float*)alloc((size_t)N * 64 * 4);
    float* hB   = (float*)alloc((size_t)N * 64 * 4);
    float* xl   = (float*)alloc((size_t)N * 256 * 4);
    float* xr   = (float*)alloc((size_t)N * 256 * 4);
    int* deg    = (int*)alloc((size_t)N * 4);
    int* start  = (int*)alloc((size_t)N * 4);
    int* cursor = (int*)alloc((size_t)N * 4);
    int* counter = (int*)alloc(256);
    int* rec    = (int*)alloc((size_t)E * 24 * 4 + 256);

    k_h0<<<N / 8, 256, 0, stream>>>(x, fW, fb, hA);
    k_zero<<<(N + 255) / 256, 256, 0, stream>>>(deg, counter, N);
    k_count<<<(E + 255) / 256, 256, 0, stream>>>(dstArr, deg, E);
    k_alloc<<<(N + 255) / 256, 256, 0, stream>>>(deg, counter, start, cursor, N);
    k_fill<<<(E + 255) / 256, 256, 0, stream>>>(dstArr, srcArr, eattr, feW, feb,
                                                cursor, rec, E);

    const float* hin = hA;
    for (int layer = 0; layer < 3; ++layer) {
        float* hout = (layer == 2) ? out : ((layer == 0) ? hB : hA);
        k_xlxr<<<N / 16, 256, 0, stream>>>(hin, Wl, Wr, bl, br, xl, xr);
        k_edge<<<(N * 64) / 256, 256, 0, stream>>>(
            (const float4*)xl, (const float4*)xr, att, (const float4*)We,
            rec, start, deg, bias, hout, N);
        hin = hout;
    }
}